// Round 3
// baseline (784.034 us; speedup 1.0000x reference)
//
#include <hip/hip_runtime.h>
#include <math.h>

#define NPTS 1024
#define BB 2
#define KNN 20
#define ROWS 2048
#define CATC 960
#define TT 3
typedef unsigned long long ull;

__device__ __forceinline__ float lrelu_f(float x){ return x >= 0.f ? x : 0.2f*x; }

// ===================== GEMM device: 64x64 tile, NT =====================
// C[bm..+64][bn..+64] += over k in [kb, kb+K): A[m][k]*B[n][k]
__device__ __forceinline__ void gemm_dev(const float* __restrict__ A, int lda,
    const float* __restrict__ B, int ldb, float* __restrict__ C, int ldc,
    int K, int kb, int bm, int bn, int tid, float* sm)
{
  float (*As)[68] = (float(*)[68])sm;
  float (*Bs)[68] = (float(*)[68])(sm + 16*68);
  const int tx = tid & 15, ty = tid >> 4;
  const int lr = tid >> 2, kq = tid & 3;
  float acc[4][4] = {};
  if ((K & 15) == 0) {
    const float* pA = A + (size_t)(bm+lr)*lda + kb + kq*4;
    const float* pB = B + (size_t)(bn+lr)*ldb + kb + kq*4;
    float4 av = *(const float4*)pA;
    float4 bv = *(const float4*)pB;
    for (int k0 = 0; k0 < K; k0 += 16) {
      As[kq*4+0][lr]=av.x; As[kq*4+1][lr]=av.y; As[kq*4+2][lr]=av.z; As[kq*4+3][lr]=av.w;
      Bs[kq*4+0][lr]=bv.x; Bs[kq*4+1][lr]=bv.y; Bs[kq*4+2][lr]=bv.z; Bs[kq*4+3][lr]=bv.w;
      __syncthreads();
      if (k0 + 16 < K) {
        av = *(const float4*)(pA + k0 + 16);
        bv = *(const float4*)(pB + k0 + 16);
      }
#pragma unroll
      for (int kk = 0; kk < 16; ++kk) {
        float4 a4 = *(const float4*)&As[kk][ty*4];
        float4 b4 = *(const float4*)&Bs[kk][tx*4];
        float ar[4]={a4.x,a4.y,a4.z,a4.w}, br[4]={b4.x,b4.y,b4.z,b4.w};
#pragma unroll
        for (int i=0;i<4;++i)
#pragma unroll
          for (int j=0;j<4;++j) acc[i][j]=fmaf(ar[i],br[j],acc[i][j]);
      }
      __syncthreads();
    }
  } else {
    for (int k0 = 0; k0 < K; k0 += 16) {
#pragma unroll
      for (int e=0;e<4;++e){
        int gk = k0 + kq*4 + e;
        As[kq*4+e][lr] = (gk<K)? A[(size_t)(bm+lr)*lda+kb+gk] : 0.f;
        Bs[kq*4+e][lr] = (gk<K)? B[(size_t)(bn+lr)*ldb+kb+gk] : 0.f;
      }
      __syncthreads();
#pragma unroll
      for (int kk = 0; kk < 16; ++kk) {
        float4 a4 = *(const float4*)&As[kk][ty*4];
        float4 b4 = *(const float4*)&Bs[kk][tx*4];
        float ar[4]={a4.x,a4.y,a4.z,a4.w}, br[4]={b4.x,b4.y,b4.z,b4.w};
#pragma unroll
        for (int i=0;i<4;++i)
#pragma unroll
          for (int j=0;j<4;++j) acc[i][j]=fmaf(ar[i],br[j],acc[i][j]);
      }
      __syncthreads();
    }
  }
#pragma unroll
  for (int i=0;i<4;++i){
    float4 v; v.x=acc[i][0]; v.y=acc[i][1]; v.z=acc[i][2]; v.w=acc[i][3];
    *(float4*)&C[(size_t)(bm+ty*4+i)*ldc + bn + tx*4] = v;
  }
}

// ===================== popcount KNN device (exact int distances) =====================
template<int W>
__device__ __forceinline__ void knn_dev(const ull* __restrict__ pk, int* __restrict__ idx,
    double* __restrict__ S12, int bid, int tid, ull* rows, volatile ull* wsh)
{
  const int n = bid & (NPTS-1), b = bid >> 10;
  if (bid == 0) { for (int j=tid; j<1024; j+=256) S12[j]=0.0; }
  const ull* pb = pk + (size_t)b*NPTS*W;
  for (int j=tid; j<NPTS*W; j+=256){ int r=j/W, w=j-r*W; rows[w*NPTS+r]=pb[j]; }
  __syncthreads();
  ull cw[W]; int pn=0;
#pragma unroll
  for (int w=0;w<W;++w){ cw[w]=rows[w*NPTS+n]; pn += __popcll(cw[w]); }
  unsigned keys[4];
#pragma unroll
  for (int mi=0;mi<4;++mi){
    int m = tid + mi*256;
    int inner=0, pm=0;
#pragma unroll
    for (int w=0;w<W;++w){ ull rm = rows[w*NPTS+m]; inner += __popcll(rm & cw[w]); pm += __popcll(rm); }
    int d = 2*inner - pn - pm;
    keys[mi] = ((unsigned)(d + 1024) << 11) | (unsigned)(NPTS-1-m);
  }
  int* out = idx + (size_t)bid*KNN;
  const int lane = tid & 63, wid = tid >> 6;
  for (int s=0;s<KNN;++s){
    unsigned loc = keys[0];
    if (keys[1]>loc) loc=keys[1];
    if (keys[2]>loc) loc=keys[2];
    if (keys[3]>loc) loc=keys[3];
#pragma unroll
    for (int off=32; off>0; off>>=1){ unsigned o=__shfl_xor(loc,off); if(o>loc)loc=o; }
    if (lane==0) wsh[wid]=loc;
    __syncthreads();
    if (tid==0){
      ull wv = wsh[0]; if(wsh[1]>wv)wv=wsh[1]; if(wsh[2]>wv)wv=wsh[2]; if(wsh[3]>wv)wv=wsh[3];
      wsh[4]=wv; out[s] = NPTS-1-(int)((unsigned)wv & 0x7FFu);
    }
    __syncthreads();
    unsigned wv = (unsigned)wsh[4];
#pragma unroll
    for (int mi=0;mi<4;++mi) if (keys[mi]==wv) keys[mi]=0u;
  }
}

// ============ layer-0 fused negdist+topk (fp32, exact ref op order) ============
__device__ __forceinline__ void ndtopk_dev(const float* __restrict__ f0, const float* __restrict__ x2,
    int* __restrict__ idx0, int bid, int tid, float* fb, float* x2s, volatile ull* wsh)
{
  const int n = bid & (NPTS-1), b = bid >> 10;
  const float* fsrc = f0 + (size_t)b*3*NPTS;
  for (int j=tid; j<3*NPTS; j+=256){ int r=j/3, c=j-r*3; fb[c*NPTS + r] = fsrc[j]; }
  for (int j=tid; j<NPTS; j+=256) x2s[j] = x2[b*NPTS + j];
  __syncthreads();
  float fn0=fb[n], fn1=fb[NPTS+n], fn2=fb[2*NPTS+n], x2n=x2s[n];
  ull keys[4];
#pragma unroll
  for (int mi=0;mi<4;++mi){
    int m = tid + mi*256;
    float inner = __fadd_rn(__fadd_rn(__fmul_rn(fn0,fb[m]), __fmul_rn(fn1,fb[NPTS+m])),
                            __fmul_rn(fn2,fb[2*NPTS+m]));
    float v = __fsub_rn(__fsub_rn(__fmul_rn(2.f,inner), x2n), x2s[m]);
    unsigned u = __float_as_uint(v);
    u = (u & 0x80000000u) ? ~u : (u | 0x80000000u);
    keys[mi] = ((ull)u << 32) | (unsigned)(NPTS-1-m);
  }
  int* out = idx0 + (size_t)bid*KNN;
  const int lane = tid & 63, wid = tid >> 6;
  for (int s=0;s<KNN;++s){
    ull loc = keys[0];
    if(keys[1]>loc)loc=keys[1];
    if(keys[2]>loc)loc=keys[2];
    if(keys[3]>loc)loc=keys[3];
#pragma unroll
    for (int off=32; off>0; off>>=1){ ull o=__shfl_xor(loc,off); if(o>loc)loc=o; }
    if (lane==0) wsh[wid]=loc;
    __syncthreads();
    if (tid==0){
      ull wv=wsh[0]; if(wsh[1]>wv)wv=wsh[1]; if(wsh[2]>wv)wv=wsh[2]; if(wsh[3]>wv)wv=wsh[3];
      wsh[4]=wv; out[s] = NPTS-1-(int)((unsigned)(wv & 0xFFFFFFFFull));
    }
    __syncthreads();
    ull wv = wsh[4];
#pragma unroll
    for (int mi=0;mi<4;++mi) if (keys[mi]==wv) keys[mi]=0ull;
  }
}

// ===================== BN+LIF device =====================
__device__ __forceinline__ void bnlif_dev(int i, int oShift,
    const float* __restrict__ hmax, const double* __restrict__ S1, const double* __restrict__ S2,
    const float* __restrict__ g, const float* __restrict__ bb,
    const float* __restrict__ pmd, const float* __restrict__ pta,
    const float* __restrict__ prd, const float* __restrict__ ptb,
    float* __restrict__ stM, float* __restrict__ stT, float* __restrict__ stR,
    float* __restrict__ sout, int offOut, ull* __restrict__ pk, int init, int laneTid)
{
  int O = 1 << oShift;
  int bn = i >> oShift;
  int o  = i & (O - 1);
  double cnt = (double)ROWS * (double)KNN;
  double mu = S1[o] / cnt;
  double vv = S2[o] / cnt - mu*mu;
  float mean = (float)mu;
  float inv  = 1.f / sqrtf((float)vv + 1e-5f);
  float h = hmax[i];
  h = ((h - mean) * inv) * g[o] + bb[o];
  h = lrelu_f(h);
  float md = fminf(fmaxf(pmd[o], 0.1f), 0.99f);
  float ta = fminf(fmaxf(pta[o], 0.001f), 0.1f);
  float rd = fminf(fmaxf(prd[o], 0.1f), 0.95f);
  float tb = ptb[o];
  float M, T, R;
  if (init) { M = 0.f; T = tb; R = 0.f; }
  else      { M = stM[i]; T = stT[i]; R = stR[i]; }
  float xv = (R <= 0.f) ? h : 0.f;
  M = M * md * (1.f - R) + xv;
  float sp = (M - T > 0.f) ? 1.f : 0.f;
  M = M * (1.f - sp);
  R = R * rd + sp;
  T = tb + (T + ta*sp - tb) * 0.95f;
  stM[i] = M; stT[i] = T; stR[i] = R;
  sout[(size_t)bn*CATC + offOut + o] = sp;
  ull ball = __ballot(sp != 0.f);
  if ((laneTid & 63) == 0) pk[i >> 6] = ball;
}

// ===================== aggregator finalize device =====================
__device__ __forceinline__ void aggfin_dev(const float* __restrict__ pA, const float* __restrict__ pB,
    const float* __restrict__ gm, const float* __restrict__ bmv, float* __restrict__ pooled,
    int o, int tid, char* smraw)
{
  double* sd1 = (double*)smraw; double* sd2 = sd1 + 256;
  float* sm0 = (float*)(sd2 + 256); float* sm1 = sm0 + 256;
  double s1=0.0, s2=0.0; float m0=-INFINITY, m1=-INFINITY;
  for (int r=tid; r<ROWS; r+=256){
    float v = __fadd_rn(pA[(size_t)r*512+o], pB[(size_t)r*512+o]);
    s1 += (double)v; s2 += (double)v*(double)v;
    if (r < NPTS) m0 = fmaxf(m0, v); else m1 = fmaxf(m1, v);
  }
  sd1[tid]=s1; sd2[tid]=s2; sm0[tid]=m0; sm1[tid]=m1;
  __syncthreads();
  for (int off=128; off>0; off>>=1){
    if (tid<off){
      sd1[tid]+=sd1[tid+off]; sd2[tid]+=sd2[tid+off];
      sm0[tid]=fmaxf(sm0[tid],sm0[tid+off]);
      sm1[tid]=fmaxf(sm1[tid],sm1[tid+off]);
    }
    __syncthreads();
  }
  if (tid==0){
    double mean = sd1[0]/(double)ROWS;
    float var = (float)(sd2[0]/(double)ROWS - mean*mean);
    float m = (float)mean;
    float inv = 1.f/sqrtf(var + 1e-5f);
    pooled[o]       = lrelu_f(((sm0[0]-m)*inv)*gm[o] + bmv[o]);
    pooled[512 + o] = lrelu_f(((sm1[0]-m)*inv)*gm[o] + bmv[o]);
  }
}

// ===================== kernels =====================
__device__ __forceinline__ void wcat_dev(const float* __restrict__ W, float* __restrict__ out,
                                         int O, int C, int i)
{
  if (i >= 2*O*C) return;
  int r = i / C, c = i - r*C;
  out[i] = (r < O) ? __fadd_rn(W[(size_t)r*2*C + c], W[(size_t)r*2*C + C + c])
                   : W[(size_t)(r-O)*2*C + c];
}

__global__ __launch_bounds__(256) void k_setup(const float* __restrict__ x,
    float* __restrict__ f0, float* __restrict__ x2,
    const float* W0, const float* W1, const float* W2, const float* W3,
    float* wc0, float* wc1, float* wc2, float* wc3, double* S12_0)
{
  int bid = blockIdx.x, tid = threadIdx.x;
  if (bid < 24) {
    int i = bid*256 + tid;
    int b = i / 3072, rem = i - b*3072, n = rem/3, c = rem - n*3;
    f0[i] = x[(size_t)b*3072 + c*NPTS + n];
  } else if (bid < 32) {
    int r = (bid-24)*256 + tid;
    int b = r >> 10, n = r & (NPTS-1);
    const float* xb = x + (size_t)b*3072;
    float a0=xb[n], a1=xb[NPTS+n], a2=xb[2*NPTS+n];
    x2[r] = __fadd_rn(__fadd_rn(__fmul_rn(a0,a0),__fmul_rn(a1,a1)),__fmul_rn(a2,a2));
  } else if (bid < 33) {
    for (int j=tid; j<1024; j+=256) S12_0[j]=0.0;
  } else if (bid < 35) {
    int i = (bid-33)*256+tid; wcat_dev(W0, wc0, 64, 3, i);
  } else if (bid < 99) {
    int i = (bid-35)*256+tid; wcat_dev(W1, wc1, 128, 64, i);
  } else if (bid < 355) {
    int i = (bid-99)*256+tid; wcat_dev(W2, wc2, 256, 128, i);
  } else {
    int i = (bid-355)*256+tid; wcat_dev(W3, wc3, 512, 256, i);
  }
}

// negd+topk (2048 blocks) + conv0 GEMM (64 blocks)
__global__ __launch_bounds__(256) void k_nt0(const float* __restrict__ f0, const float* __restrict__ x2,
    int* __restrict__ idx0, const float* __restrict__ wc0, float* __restrict__ AB)
{
  __shared__ __align__(16) char sm[16384];
  __shared__ ull wsh[8];
  int bid = blockIdx.x, tid = threadIdx.x;
  if (bid < 2048) {
    ndtopk_dev(f0, x2, idx0, bid, tid, (float*)sm, (float*)sm + 3*NPTS, wsh);
  } else {
    int id = bid - 2048;          // 64 tiles: 32 x 2
    int tm = id >> 1, tn = id & 1;
    gemm_dev(f0, 3, wc0, 3, AB, 128, 3, 0, tm*64, tn*64, tid, (float*)sm);
  }
}

// split-K agg GEMM: 512 blocks (2 parts x 32 x 8 tiles)
__global__ __launch_bounds__(256) void k_agg(const float* __restrict__ scat, const float* __restrict__ Wm,
    float* __restrict__ aggA, float* __restrict__ aggB)
{
  __shared__ __align__(16) float sm[2*16*68];
  int id = blockIdx.x;
  int part = id >> 8, tl = id & 255, tm = tl >> 3, tn = tl & 7;
  gemm_dev(scat, CATC, Wm, CATC, part ? aggB : aggA, 512, 480, part*480,
           tm*64, tn*64, threadIdx.x, sm);
}

// bnlif layer-0 (512 blocks) + aggfin of previous t (512 blocks when present)
__global__ __launch_bounds__(256) void k_lif0fin(
    const float* __restrict__ hmax0, const double* __restrict__ S1_0, const double* __restrict__ S2_0,
    const float* g, const float* bb, const float* pmd, const float* pta,
    const float* prd, const float* ptb,
    float* stM, float* stT, float* stR, float* scc, ull* pk0, int init,
    const float* aggA, const float* aggB, const float* gm, const float* bmv, float* pooled)
{
  __shared__ __align__(16) char sm[6144];
  int bid = blockIdx.x, tid = threadIdx.x;
  if (bid < 512) {
    bnlif_dev(bid*256+tid, 6, hmax0, S1_0, S2_0, g, bb, pmd, pta, prd, ptb,
              stM, stT, stR, scc, 0, pk0, init, tid);
  } else {
    aggfin_dev(aggA, aggB, gm, bmv, pooled, bid-512, tid, sm);
  }
}

// knn (2048 blocks) + conv GEMM (nConv blocks)
template<int W>
__global__ __launch_bounds__(256) void k_knnconv(const ull* __restrict__ pk, int* __restrict__ idx,
    double* __restrict__ S12, const float* __restrict__ Ain, const float* __restrict__ Bw,
    float* __restrict__ AB, int twoO, int K, int ntn)
{
  constexpr int KNNB = W*NPTS*8;
  constexpr int SMSZ = (KNNB > 8704 ? KNNB : 8704);
  __shared__ __align__(16) char sm[SMSZ];
  __shared__ ull wsh[8];
  int bid = blockIdx.x, tid = threadIdx.x;
  if (bid < 2048) {
    knn_dev<W>(pk, idx, S12, bid, tid, (ull*)sm, wsh);
  } else {
    int id = bid - 2048;
    int tm = id / ntn, tn = id - tm*ntn;
    gemm_dev(Ain, CATC, Bw, K, AB, twoO, K, 0, tm*64, tn*64, tid, (float*)sm);
  }
}

// gather neighbors, per-(b,n,o) max_k, per-channel sum / sumsq (fp64 atomics)
__global__ __launch_bounds__(256) void k_gather(const float* __restrict__ AB, int O,
    const int* __restrict__ idx, float* __restrict__ hmax,
    double* __restrict__ S1, double* __restrict__ S2)
{
  int base = blockIdx.x * 8;
  __shared__ int sidx[8*KNN];
  for (int i = threadIdx.x; i < 8*KNN; i += blockDim.x)
    sidx[i] = idx[(size_t)base*KNN + i];
  __syncthreads();
  int twoO = 2*O;
  for (int o = threadIdx.x; o < O; o += blockDim.x) {
    double ts1 = 0.0, ts2 = 0.0;
    for (int r = 0; r < 8; ++r) {
      int bn = base + r;
      int b = bn >> 10;
      float bc = AB[(size_t)bn*twoO + O + o];
      float mx = -INFINITY;
      double s1 = 0.0, s2 = 0.0;
#pragma unroll
      for (int k = 0; k < KNN; ++k) {
        int m = sidx[r*KNN + k];
        float a = AB[((size_t)(b*NPTS + m))*twoO + o];
        mx = fmaxf(mx, a);
        s1 += (double)a;
        s2 += (double)a * (double)a;
      }
      hmax[(size_t)bn*O + o] = mx - bc;
      ts1 += s1 - (double)KNN * (double)bc;
      ts2 += s2 - 2.0*(double)bc*s1 + (double)KNN*(double)bc*(double)bc;
    }
    atomicAdd(&S1[o], ts1);
    atomicAdd(&S2[o], ts2);
  }
}

__global__ __launch_bounds__(256) void k_bnlif(const float* __restrict__ hmax, int oShift,
    const double* __restrict__ S1, const double* __restrict__ S2,
    const float* g, const float* bb, const float* pmd, const float* pta,
    const float* prd, const float* ptb,
    float* stM, float* stT, float* stR, float* scc, int offOut, ull* pk, int init)
{
  bnlif_dev(blockIdx.x*256 + threadIdx.x, oShift, hmax, S1, S2, g, bb, pmd, pta, prd, ptb,
            stM, stT, stR, scc, offOut, pk, init, threadIdx.x);
}

__global__ __launch_bounds__(256) void k_aggfin(const float* __restrict__ aggA,
    const float* __restrict__ aggB, const float* gm, const float* bmv, float* pooled)
{
  __shared__ __align__(16) char sm[6144];
  aggfin_dev(aggA, aggB, gm, bmv, pooled, blockIdx.x, threadIdx.x, sm);
}

__global__ __launch_bounds__(256) void k_final(const float* __restrict__ pooled,
    const float* __restrict__ tw, const float* __restrict__ lftb, float* __restrict__ out)
{
  int i = blockIdx.x*256 + threadIdx.x;
  if (i >= BB*512) return;
  int b = i / 512, o = i - b*512;
  float t0 = tw[0], t1 = tw[1], t2 = tw[2];
  float mx = fmaxf(t0, fmaxf(t1, t2));
  float e0 = expf(t0-mx), e1 = expf(t1-mx), e2 = expf(t2-mx);
  float den = e0 + e1 + e2;
  float v = (e0/den)*pooled[(0*BB+b)*512+o]
          + (e1/den)*pooled[(1*BB+b)*512+o]
          + (e2/den)*pooled[(2*BB+b)*512+o];
  out[i] = (v - lftb[o] > 0.f) ? 1.f : 0.f;
}

// ===================== host =====================
extern "C" void kernel_launch(void* const* d_in, const int* in_sizes, int n_in,
                              void* d_out, int out_size, void* d_ws, size_t ws_size,
                              hipStream_t stream)
{
  (void)in_sizes; (void)n_in; (void)out_size; (void)ws_size;
  const float* x = (const float*)d_in[0];
  const float* Wl[4] = {(const float*)d_in[1],(const float*)d_in[4],(const float*)d_in[7],(const float*)d_in[10]};
  const float* gl[4] = {(const float*)d_in[2],(const float*)d_in[5],(const float*)d_in[8],(const float*)d_in[11]};
  const float* bl[4] = {(const float*)d_in[3],(const float*)d_in[6],(const float*)d_in[9],(const float*)d_in[12]};
  const float* Wm = (const float*)d_in[13];
  const float* gm = (const float*)d_in[14];
  const float* bm = (const float*)d_in[15];
  const float* lp[5][4];
  for (int l = 0; l < 5; ++l)
    for (int q = 0; q < 4; ++q)
      lp[l][q] = (const float*)d_in[16 + l*4 + q];
  const float* tw = (const float*)d_in[36];

  // ---- workspace carve ----
  char* pw = (char*)d_ws;
  auto alloc = [&](size_t bytes)->char* {
    char* r = pw; pw += (bytes + 255) & ~(size_t)255; return r;
  };
  float* f0     = (float*)alloc((size_t)ROWS*3*sizeof(float));
  float* x2     = (float*)alloc((size_t)ROWS*sizeof(float));
  int*   idx0   = (int*)  alloc((size_t)ROWS*KNN*sizeof(int));
  int*   idxS   = (int*)  alloc((size_t)ROWS*KNN*sizeof(int));
  float* AB     = (float*)alloc((size_t)ROWS*1024*sizeof(float));
  float* hmax0  = (float*)alloc((size_t)ROWS*64*sizeof(float));
  float* hmaxS  = (float*)alloc((size_t)ROWS*512*sizeof(float));  // doubles as aggB
  float* aggA   = (float*)alloc((size_t)ROWS*512*sizeof(float));
  float* scat   = (float*)alloc((size_t)ROWS*CATC*sizeof(float));
  double* S12_0 = (double*)alloc(1024*sizeof(double));
  double* S12   = (double*)alloc(1024*sizeof(double));
  float* pooled = (float*)alloc((size_t)TT*BB*512*sizeof(float));
  ull* pkb[4];
  int Wn[4] = {1, 2, 4, 8};
  for (int i = 0; i < 4; ++i)
    pkb[i] = (ull*)alloc((size_t)ROWS*Wn[i]*sizeof(ull));

  int Cin[4]   = {3, 64, 128, 256};
  int Oo[4]    = {64, 128, 256, 512};
  int oSh[4]   = {6, 7, 8, 9};
  int offIn[4] = {0, 0, 64, 192};
  int offOut[4]= {0, 64, 192, 448};
  float *wcat[4], *stM[4], *stT[4], *stR[4];
  for (int i = 0; i < 4; ++i) {
    wcat[i] = (float*)alloc((size_t)2*Oo[i]*Cin[i]*sizeof(float));
    stM[i]  = (float*)alloc((size_t)ROWS*Oo[i]*sizeof(float));
    stT[i]  = (float*)alloc((size_t)ROWS*Oo[i]*sizeof(float));
    stR[i]  = (float*)alloc((size_t)ROWS*Oo[i]*sizeof(float));
  }
  double* S1_0 = S12_0; double* S2_0 = S12_0 + 512;
  double* S1 = S12;     double* S2 = S12 + 512;
  float* aggB = hmaxS;   // lifetime-disjoint alias

  // ---- setup ----
  k_setup<<<1379, 256, 0, stream>>>(x, f0, x2, Wl[0], Wl[1], Wl[2], Wl[3],
                                    wcat[0], wcat[1], wcat[2], wcat[3], S12_0);
  k_nt0<<<2112, 256, 0, stream>>>(f0, x2, idx0, wcat[0], AB);
  k_gather<<<256, 256, 0, stream>>>(AB, 64, idx0, hmax0, S1_0, S2_0);

  // ---- time steps ----
  for (int t = 0; t < TT; ++t) {
    int init = (t == 0) ? 1 : 0;
    if (t > 0)
      k_agg<<<512, 256, 0, stream>>>(scat, Wm, aggA, aggB);
    k_lif0fin<<<(t > 0 ? 1024 : 512), 256, 0, stream>>>(
        hmax0, S1_0, S2_0, gl[0], bl[0],
        lp[0][0], lp[0][1], lp[0][2], lp[0][3],
        stM[0], stT[0], stR[0], scat, pkb[0], init,
        aggA, aggB, gm, bm, pooled + (t > 0 ? (size_t)(t-1)*BB*512 : 0));
    for (int i = 1; i < 4; ++i) {
      int C = Cin[i], O = Oo[i];
      int twoO = 2*O, ntn = twoO/64, nConv = 32*ntn;
      const float* fin = scat + offIn[i];
      switch (Wn[i-1]) {
        case 1: k_knnconv<1><<<2048+nConv, 256, 0, stream>>>(pkb[0], idxS, S12, fin, wcat[i], AB, twoO, C, ntn); break;
        case 2: k_knnconv<2><<<2048+nConv, 256, 0, stream>>>(pkb[1], idxS, S12, fin, wcat[i], AB, twoO, C, ntn); break;
        default: k_knnconv<4><<<2048+nConv, 256, 0, stream>>>(pkb[2], idxS, S12, fin, wcat[i], AB, twoO, C, ntn); break;
      }
      k_gather<<<256, 256, 0, stream>>>(AB, O, idxS, hmaxS, S1, S2);
      k_bnlif<<<(ROWS*O)/256, 256, 0, stream>>>(
          hmaxS, oSh[i], S1, S2, gl[i], bl[i],
          lp[i][0], lp[i][1], lp[i][2], lp[i][3],
          stM[i], stT[i], stR[i], scat, offOut[i], pkb[i], init);
    }
  }
  // ---- tail: agg of t=2, finalize, output ----
  k_agg<<<512, 256, 0, stream>>>(scat, Wm, aggA, aggB);
  k_aggfin<<<512, 256, 0, stream>>>(aggA, aggB, gm, bm, pooled + (size_t)2*BB*512);
  k_final<<<4, 256, 0, stream>>>(pooled, tw, lp[4][3], (float*)d_out);
}

// Round 4
// 542.314 us; speedup vs baseline: 1.4457x; 1.4457x over previous
//
#include <hip/hip_runtime.h>
#include <math.h>

#define NPTS 1024
#define BB 2
#define KNN 20
#define ROWS 2048
#define CATC 960
#define TT 3
typedef unsigned long long ull;

__device__ __forceinline__ float lrelu_f(float x){ return x >= 0.f ? x : 0.2f*x; }

// ===================== GEMM device: 64x64 tile, NT =====================
__device__ __forceinline__ void gemm_dev(const float* __restrict__ A, int lda,
    const float* __restrict__ B, int ldb, float* __restrict__ C, int ldc,
    int K, int kb, int bm, int bn, int tid, float* sm)
{
  float (*As)[68] = (float(*)[68])sm;
  float (*Bs)[68] = (float(*)[68])(sm + 16*68);
  const int tx = tid & 15, ty = tid >> 4;
  const int lr = tid >> 2, kq = tid & 3;
  float acc[4][4] = {};
  if ((K & 15) == 0) {
    const float* pA = A + (size_t)(bm+lr)*lda + kb + kq*4;
    const float* pB = B + (size_t)(bn+lr)*ldb + kb + kq*4;
    float4 av = *(const float4*)pA;
    float4 bv = *(const float4*)pB;
    for (int k0 = 0; k0 < K; k0 += 16) {
      As[kq*4+0][lr]=av.x; As[kq*4+1][lr]=av.y; As[kq*4+2][lr]=av.z; As[kq*4+3][lr]=av.w;
      Bs[kq*4+0][lr]=bv.x; Bs[kq*4+1][lr]=bv.y; Bs[kq*4+2][lr]=bv.z; Bs[kq*4+3][lr]=bv.w;
      __syncthreads();
      if (k0 + 16 < K) {
        av = *(const float4*)(pA + k0 + 16);
        bv = *(const float4*)(pB + k0 + 16);
      }
#pragma unroll
      for (int kk = 0; kk < 16; ++kk) {
        float4 a4 = *(const float4*)&As[kk][ty*4];
        float4 b4 = *(const float4*)&Bs[kk][tx*4];
        float ar[4]={a4.x,a4.y,a4.z,a4.w}, br[4]={b4.x,b4.y,b4.z,b4.w};
#pragma unroll
        for (int i=0;i<4;++i)
#pragma unroll
          for (int j=0;j<4;++j) acc[i][j]=fmaf(ar[i],br[j],acc[i][j]);
      }
      __syncthreads();
    }
  } else {
    for (int k0 = 0; k0 < K; k0 += 16) {
#pragma unroll
      for (int e=0;e<4;++e){
        int gk = k0 + kq*4 + e;
        As[kq*4+e][lr] = (gk<K)? A[(size_t)(bm+lr)*lda+kb+gk] : 0.f;
        Bs[kq*4+e][lr] = (gk<K)? B[(size_t)(bn+lr)*ldb+kb+gk] : 0.f;
      }
      __syncthreads();
#pragma unroll
      for (int kk = 0; kk < 16; ++kk) {
        float4 a4 = *(const float4*)&As[kk][ty*4];
        float4 b4 = *(const float4*)&Bs[kk][tx*4];
        float ar[4]={a4.x,a4.y,a4.z,a4.w}, br[4]={b4.x,b4.y,b4.z,b4.w};
#pragma unroll
        for (int i=0;i<4;++i)
#pragma unroll
          for (int j=0;j<4;++j) acc[i][j]=fmaf(ar[i],br[j],acc[i][j]);
      }
      __syncthreads();
    }
  }
#pragma unroll
  for (int i=0;i<4;++i){
    float4 v; v.x=acc[i][0]; v.y=acc[i][1]; v.z=acc[i][2]; v.w=acc[i][3];
    *(float4*)&C[(size_t)(bm+ty*4+i)*ldc + bn + tx*4] = v;
  }
}

// ============ wave-level popcount KNN: one wave per row, no LDS, no barriers ============
template<int W>
__device__ __forceinline__ void knn_wave(const ull* __restrict__ pk, int* __restrict__ idx,
                                         int row, int lane)
{
  const int n = row & (NPTS-1), b = row >> 10;
  const ull* pb = pk + (size_t)b*NPTS*W;
  ull cw[W]; int pn = 0;
#pragma unroll
  for (int w=0; w<W; ++w){ cw[w] = pb[(size_t)n*W + w]; pn += __popcll(cw[w]); }
  unsigned keys[16];
#pragma unroll 4
  for (int i=0;i<16;++i){
    int m = lane + (i<<6);
    int inner=0, pm=0;
#pragma unroll
    for (int w=0;w<W;++w){
      ull rm = pb[(size_t)m*W + w];
      inner += __popcll(rm & cw[w]);
      pm    += __popcll(rm);
    }
    int d = 2*inner - pn - pm;                     // exact, in [-512, 0]
    keys[i] = ((unsigned)(d+1024)<<11) | (unsigned)(NPTS-1-m);
  }
  unsigned lmax = keys[0];
#pragma unroll
  for (int i=1;i<16;++i) lmax = keys[i]>lmax ? keys[i] : lmax;
  unsigned mywin = 0;
  for (int s=0;s<KNN;++s){
    unsigned v = lmax;
#pragma unroll
    for (int off=1; off<64; off<<=1){ unsigned o = __shfl_xor(v, off, 64); if (o>v) v=o; }
    if (lane == s) mywin = (unsigned)(NPTS-1) - (v & 0x7FFu);
    if (lmax == v){                                // unique owner
#pragma unroll
      for (int i=0;i<16;++i) if (keys[i]==v) keys[i]=0u;
      lmax = keys[0];
#pragma unroll
      for (int i=1;i<16;++i) lmax = keys[i]>lmax ? keys[i] : lmax;
    }
  }
  if (lane < KNN) idx[(size_t)row*KNN + lane] = (int)mywin;
}

// ============ wave-level layer-0 KNN (fp32, exact ref op order) ============
__device__ __forceinline__ void knn0_wave(const float* __restrict__ x, const float* __restrict__ x2,
                                          int* __restrict__ idx, int row, int lane)
{
  const int n = row & (NPTS-1), b = row >> 10;
  const float* xb = x + (size_t)b*3*NPTS;
  float fn0 = xb[n], fn1 = xb[NPTS+n], fn2 = xb[2*NPTS+n];
  float x2n = x2[row];
  ull keys[16];
#pragma unroll 4
  for (int i=0;i<16;++i){
    int m = lane + (i<<6);
    float inner = __fadd_rn(__fadd_rn(__fmul_rn(fn0, xb[m]), __fmul_rn(fn1, xb[NPTS+m])),
                            __fmul_rn(fn2, xb[2*NPTS+m]));
    float v = __fsub_rn(__fsub_rn(__fmul_rn(2.f, inner), x2n), x2[(b<<10)+m]);
    unsigned u = __float_as_uint(v);
    u = (u & 0x80000000u) ? ~u : (u | 0x80000000u);
    keys[i] = ((ull)u << 32) | (unsigned)(NPTS-1-m);
  }
  ull lmax = keys[0];
#pragma unroll
  for (int i=1;i<16;++i) lmax = keys[i]>lmax ? keys[i] : lmax;
  unsigned mywin = 0;
  for (int s=0;s<KNN;++s){
    ull v = lmax;
#pragma unroll
    for (int off=1; off<64; off<<=1){ ull o = __shfl_xor(v, off, 64); if (o>v) v=o; }
    if (lane == s) mywin = (unsigned)(NPTS-1) - (unsigned)(v & 0xFFFFFFFFull);
    if (lmax == v){
#pragma unroll
      for (int i=0;i<16;++i) if (keys[i]==v) keys[i]=0ull;
      lmax = keys[0];
#pragma unroll
      for (int i=1;i<16;++i) lmax = keys[i]>lmax ? keys[i] : lmax;
    }
  }
  if (lane < KNN) idx[(size_t)row*KNN + lane] = (int)mywin;
}

// ===================== BN+LIF device =====================
__device__ __forceinline__ void bnlif_dev(int i, int oShift,
    const float* __restrict__ hmax, const double* __restrict__ S1, const double* __restrict__ S2,
    const float* __restrict__ g, const float* __restrict__ bb,
    const float* __restrict__ pmd, const float* __restrict__ pta,
    const float* __restrict__ prd, const float* __restrict__ ptb,
    float* __restrict__ stM, float* __restrict__ stT, float* __restrict__ stR,
    float* __restrict__ sout, int offOut, ull* __restrict__ pk, int init, int laneTid)
{
  int O = 1 << oShift;
  int bn = i >> oShift;
  int o  = i & (O - 1);
  double cnt = (double)ROWS * (double)KNN;
  double mu = S1[o] / cnt;
  double vv = S2[o] / cnt - mu*mu;
  float mean = (float)mu;
  float inv  = 1.f / sqrtf((float)vv + 1e-5f);
  float h = hmax[i];
  h = ((h - mean) * inv) * g[o] + bb[o];
  h = lrelu_f(h);
  float md = fminf(fmaxf(pmd[o], 0.1f), 0.99f);
  float ta = fminf(fmaxf(pta[o], 0.001f), 0.1f);
  float rd = fminf(fmaxf(prd[o], 0.1f), 0.95f);
  float tb = ptb[o];
  float M, T, R;
  if (init) { M = 0.f; T = tb; R = 0.f; }
  else      { M = stM[i]; T = stT[i]; R = stR[i]; }
  float xv = (R <= 0.f) ? h : 0.f;
  M = M * md * (1.f - R) + xv;
  float sp = (M - T > 0.f) ? 1.f : 0.f;
  M = M * (1.f - sp);
  R = R * rd + sp;
  T = tb + (T + ta*sp - tb) * 0.95f;
  stM[i] = M; stT[i] = T; stR[i] = R;
  sout[(size_t)bn*CATC + offOut + o] = sp;
  ull ball = __ballot(sp != 0.f);
  if ((laneTid & 63) == 0) pk[i >> 6] = ball;
}

// ===================== aggregator finalize device =====================
__device__ __forceinline__ void aggfin_dev(const float* __restrict__ pA, const float* __restrict__ pB,
    const float* __restrict__ gm, const float* __restrict__ bmv, float* __restrict__ pooled,
    int o, int tid, char* smraw)
{
  double* sd1 = (double*)smraw; double* sd2 = sd1 + 256;
  float* sm0 = (float*)(sd2 + 256); float* sm1 = sm0 + 256;
  double s1=0.0, s2=0.0; float m0=-INFINITY, m1=-INFINITY;
  for (int r=tid; r<ROWS; r+=256){
    float v = __fadd_rn(pA[(size_t)r*512+o], pB[(size_t)r*512+o]);
    s1 += (double)v; s2 += (double)v*(double)v;
    if (r < NPTS) m0 = fmaxf(m0, v); else m1 = fmaxf(m1, v);
  }
  sd1[tid]=s1; sd2[tid]=s2; sm0[tid]=m0; sm1[tid]=m1;
  __syncthreads();
  for (int off=128; off>0; off>>=1){
    if (tid<off){
      sd1[tid]+=sd1[tid+off]; sd2[tid]+=sd2[tid+off];
      sm0[tid]=fmaxf(sm0[tid],sm0[tid+off]);
      sm1[tid]=fmaxf(sm1[tid],sm1[tid+off]);
    }
    __syncthreads();
  }
  if (tid==0){
    double mean = sd1[0]/(double)ROWS;
    float var = (float)(sd2[0]/(double)ROWS - mean*mean);
    float m = (float)mean;
    float inv = 1.f/sqrtf(var + 1e-5f);
    pooled[o]       = lrelu_f(((sm0[0]-m)*inv)*gm[o] + bmv[o]);
    pooled[512 + o] = lrelu_f(((sm1[0]-m)*inv)*gm[o] + bmv[o]);
  }
}

// ===================== kernels =====================
__device__ __forceinline__ void wcat_dev(const float* __restrict__ W, float* __restrict__ out,
                                         int O, int C, int i)
{
  if (i >= 2*O*C) return;
  int r = i / C, c = i - r*C;
  out[i] = (r < O) ? __fadd_rn(W[(size_t)r*2*C + c], W[(size_t)r*2*C + C + c])
                   : W[(size_t)(r-O)*2*C + c];
}

__global__ __launch_bounds__(256) void k_setup(const float* __restrict__ x,
    float* __restrict__ f0, float* __restrict__ x2,
    const float* W0, const float* W1, const float* W2, const float* W3,
    float* wc0, float* wc1, float* wc2, float* wc3, double* S12_0)
{
  int bid = blockIdx.x, tid = threadIdx.x;
  if (bid < 24) {
    int i = bid*256 + tid;
    int b = i / 3072, rem = i - b*3072, n = rem/3, c = rem - n*3;
    f0[i] = x[(size_t)b*3072 + c*NPTS + n];
  } else if (bid < 32) {
    int r = (bid-24)*256 + tid;
    int b = r >> 10, n = r & (NPTS-1);
    const float* xb = x + (size_t)b*3072;
    float a0=xb[n], a1=xb[NPTS+n], a2=xb[2*NPTS+n];
    x2[r] = __fadd_rn(__fadd_rn(__fmul_rn(a0,a0),__fmul_rn(a1,a1)),__fmul_rn(a2,a2));
  } else if (bid < 33) {
    for (int j=tid; j<1024; j+=256) S12_0[j]=0.0;
  } else if (bid < 35) {
    int i = (bid-33)*256+tid; wcat_dev(W0, wc0, 64, 3, i);
  } else if (bid < 99) {
    int i = (bid-35)*256+tid; wcat_dev(W1, wc1, 128, 64, i);
  } else if (bid < 355) {
    int i = (bid-99)*256+tid; wcat_dev(W2, wc2, 256, 128, i);
  } else {
    int i = (bid-355)*256+tid; wcat_dev(W3, wc3, 512, 256, i);
  }
}

// layer-0: 512 knn-wave blocks + 64 conv0 GEMM tiles
__global__ __launch_bounds__(256) void k_nt0v2(const float* __restrict__ x, const float* __restrict__ x2,
    int* __restrict__ idx0, const float* __restrict__ f0, const float* __restrict__ wc0,
    float* __restrict__ AB)
{
  __shared__ __align__(16) float sm[2*16*68];
  int bid = blockIdx.x, tid = threadIdx.x;
  if (bid < 512) {
    knn0_wave(x, x2, idx0, bid*4 + (tid>>6), tid & 63);
  } else {
    int id = bid - 512;
    gemm_dev(f0, 3, wc0, 3, AB, 128, 3, 0, (id>>1)*64, (id&1)*64, tid, sm);
  }
}

// loop layers: 512 knn-wave blocks (no LDS, no barriers) + conv GEMM tiles
template<int W>
__global__ __launch_bounds__(256) void k_knnconv2(const ull* __restrict__ pk, int* __restrict__ idx,
    double* __restrict__ S12, const float* __restrict__ Ain, const float* __restrict__ Bw,
    float* __restrict__ AB, int twoO, int K, int ntn)
{
  __shared__ __align__(16) float sm[2*16*68];
  int bid = blockIdx.x, tid = threadIdx.x;
  if (bid < 512) {
    if (bid == 0) { for (int j=tid; j<1024; j+=256) S12[j]=0.0; }
    knn_wave<W>(pk, idx, bid*4 + (tid>>6), tid & 63);
  } else {
    int id = bid - 512;
    int tm = id / ntn, tn = id - tm*ntn;
    gemm_dev(Ain, CATC, Bw, K, AB, twoO, K, 0, tm*64, tn*64, tid, sm);
  }
}

// split-K agg GEMM: 512 blocks (2 parts x 32 x 8 tiles)
__global__ __launch_bounds__(256) void k_agg(const float* __restrict__ scat, const float* __restrict__ Wm,
    float* __restrict__ aggA, float* __restrict__ aggB)
{
  __shared__ __align__(16) float sm[2*16*68];
  int id = blockIdx.x;
  int part = id >> 8, tl = id & 255, tm = tl >> 3, tn = tl & 7;
  gemm_dev(scat, CATC, Wm, CATC, part ? aggB : aggA, 512, 480, part*480,
           tm*64, tn*64, threadIdx.x, sm);
}

// bnlif layer-0 (512 blocks) + aggfin of previous t (512 blocks when present)
__global__ __launch_bounds__(256) void k_lif0fin(
    const float* __restrict__ hmax0, const double* __restrict__ S1_0, const double* __restrict__ S2_0,
    const float* g, const float* bb, const float* pmd, const float* pta,
    const float* prd, const float* ptb,
    float* stM, float* stT, float* stR, float* scc, ull* pk0, int init,
    const float* aggA, const float* aggB, const float* gm, const float* bmv, float* pooled)
{
  __shared__ __align__(16) char sm[6144];
  int bid = blockIdx.x, tid = threadIdx.x;
  if (bid < 512) {
    bnlif_dev(bid*256+tid, 6, hmax0, S1_0, S2_0, g, bb, pmd, pta, prd, ptb,
              stM, stT, stR, scc, 0, pk0, init, tid);
  } else {
    aggfin_dev(aggA, aggB, gm, bmv, pooled, bid-512, tid, sm);
  }
}

// gather neighbors, per-(b,n,o) max_k, per-channel sum / sumsq (fp64 atomics)
__global__ __launch_bounds__(256) void k_gather(const float* __restrict__ AB, int O,
    const int* __restrict__ idx, float* __restrict__ hmax,
    double* __restrict__ S1, double* __restrict__ S2)
{
  int base = blockIdx.x * 8;
  __shared__ int sidx[8*KNN];
  for (int i = threadIdx.x; i < 8*KNN; i += blockDim.x)
    sidx[i] = idx[(size_t)base*KNN + i];
  __syncthreads();
  int twoO = 2*O;
  for (int o = threadIdx.x; o < O; o += blockDim.x) {
    double ts1 = 0.0, ts2 = 0.0;
    for (int r = 0; r < 8; ++r) {
      int bn = base + r;
      int b = bn >> 10;
      float bc = AB[(size_t)bn*twoO + O + o];
      float mx = -INFINITY;
      double s1 = 0.0, s2 = 0.0;
#pragma unroll
      for (int k = 0; k < KNN; ++k) {
        int m = sidx[r*KNN + k];
        float a = AB[((size_t)(b*NPTS + m))*twoO + o];
        mx = fmaxf(mx, a);
        s1 += (double)a;
        s2 += (double)a * (double)a;
      }
      hmax[(size_t)bn*O + o] = mx - bc;
      ts1 += s1 - (double)KNN * (double)bc;
      ts2 += s2 - 2.0*(double)bc*s1 + (double)KNN*(double)bc*(double)bc;
    }
    atomicAdd(&S1[o], ts1);
    atomicAdd(&S2[o], ts2);
  }
}

__global__ __launch_bounds__(256) void k_bnlif(const float* __restrict__ hmax, int oShift,
    const double* __restrict__ S1, const double* __restrict__ S2,
    const float* g, const float* bb, const float* pmd, const float* pta,
    const float* prd, const float* ptb,
    float* stM, float* stT, float* stR, float* scc, int offOut, ull* pk, int init)
{
  bnlif_dev(blockIdx.x*256 + threadIdx.x, oShift, hmax, S1, S2, g, bb, pmd, pta, prd, ptb,
            stM, stT, stR, scc, offOut, pk, init, threadIdx.x);
}

__global__ __launch_bounds__(256) void k_aggfin(const float* __restrict__ aggA,
    const float* __restrict__ aggB, const float* gm, const float* bmv, float* pooled)
{
  __shared__ __align__(16) char sm[6144];
  aggfin_dev(aggA, aggB, gm, bmv, pooled, blockIdx.x, threadIdx.x, sm);
}

__global__ __launch_bounds__(256) void k_final(const float* __restrict__ pooled,
    const float* __restrict__ tw, const float* __restrict__ lftb, float* __restrict__ out)
{
  int i = blockIdx.x*256 + threadIdx.x;
  if (i >= BB*512) return;
  int b = i / 512, o = i - b*512;
  float t0 = tw[0], t1 = tw[1], t2 = tw[2];
  float mx = fmaxf(t0, fmaxf(t1, t2));
  float e0 = expf(t0-mx), e1 = expf(t1-mx), e2 = expf(t2-mx);
  float den = e0 + e1 + e2;
  float v = (e0/den)*pooled[(0*BB+b)*512+o]
          + (e1/den)*pooled[(1*BB+b)*512+o]
          + (e2/den)*pooled[(2*BB+b)*512+o];
  out[i] = (v - lftb[o] > 0.f) ? 1.f : 0.f;
}

// ===================== host =====================
extern "C" void kernel_launch(void* const* d_in, const int* in_sizes, int n_in,
                              void* d_out, int out_size, void* d_ws, size_t ws_size,
                              hipStream_t stream)
{
  (void)in_sizes; (void)n_in; (void)out_size; (void)ws_size;
  const float* x = (const float*)d_in[0];
  const float* Wl[4] = {(const float*)d_in[1],(const float*)d_in[4],(const float*)d_in[7],(const float*)d_in[10]};
  const float* gl[4] = {(const float*)d_in[2],(const float*)d_in[5],(const float*)d_in[8],(const float*)d_in[11]};
  const float* bl[4] = {(const float*)d_in[3],(const float*)d_in[6],(const float*)d_in[9],(const float*)d_in[12]};
  const float* Wm = (const float*)d_in[13];
  const float* gm = (const float*)d_in[14];
  const float* bm = (const float*)d_in[15];
  const float* lp[5][4];
  for (int l = 0; l < 5; ++l)
    for (int q = 0; q < 4; ++q)
      lp[l][q] = (const float*)d_in[16 + l*4 + q];
  const float* tw = (const float*)d_in[36];

  // ---- workspace carve ----
  char* pw = (char*)d_ws;
  auto alloc = [&](size_t bytes)->char* {
    char* r = pw; pw += (bytes + 255) & ~(size_t)255; return r;
  };
  float* f0     = (float*)alloc((size_t)ROWS*3*sizeof(float));
  float* x2     = (float*)alloc((size_t)ROWS*sizeof(float));
  int*   idx0   = (int*)  alloc((size_t)ROWS*KNN*sizeof(int));
  int*   idxS   = (int*)  alloc((size_t)ROWS*KNN*sizeof(int));
  float* AB     = (float*)alloc((size_t)ROWS*1024*sizeof(float));
  float* hmax0  = (float*)alloc((size_t)ROWS*64*sizeof(float));
  float* hmaxS  = (float*)alloc((size_t)ROWS*512*sizeof(float));  // doubles as aggB
  float* aggA   = (float*)alloc((size_t)ROWS*512*sizeof(float));
  float* scat   = (float*)alloc((size_t)ROWS*CATC*sizeof(float));
  double* S12_0 = (double*)alloc(1024*sizeof(double));
  double* S12   = (double*)alloc(1024*sizeof(double));
  float* pooled = (float*)alloc((size_t)TT*BB*512*sizeof(float));
  ull* pkb[4];
  int Wn[4] = {1, 2, 4, 8};
  for (int i = 0; i < 4; ++i)
    pkb[i] = (ull*)alloc((size_t)ROWS*Wn[i]*sizeof(ull));

  int Cin[4]   = {3, 64, 128, 256};
  int Oo[4]    = {64, 128, 256, 512};
  int oSh[4]   = {6, 7, 8, 9};
  int offIn[4] = {0, 0, 64, 192};
  int offOut[4]= {0, 64, 192, 448};
  float *wcat[4], *stM[4], *stT[4], *stR[4];
  for (int i = 0; i < 4; ++i) {
    wcat[i] = (float*)alloc((size_t)2*Oo[i]*Cin[i]*sizeof(float));
    stM[i]  = (float*)alloc((size_t)ROWS*Oo[i]*sizeof(float));
    stT[i]  = (float*)alloc((size_t)ROWS*Oo[i]*sizeof(float));
    stR[i]  = (float*)alloc((size_t)ROWS*Oo[i]*sizeof(float));
  }
  double* S1_0 = S12_0; double* S2_0 = S12_0 + 512;
  double* S1 = S12;     double* S2 = S12 + 512;
  float* aggB = hmaxS;   // lifetime-disjoint alias

  // ---- setup ----
  k_setup<<<1379, 256, 0, stream>>>(x, f0, x2, Wl[0], Wl[1], Wl[2], Wl[3],
                                    wcat[0], wcat[1], wcat[2], wcat[3], S12_0);
  k_nt0v2<<<576, 256, 0, stream>>>(x, x2, idx0, f0, wcat[0], AB);
  k_gather<<<256, 256, 0, stream>>>(AB, 64, idx0, hmax0, S1_0, S2_0);

  // ---- time steps ----
  for (int t = 0; t < TT; ++t) {
    int init = (t == 0) ? 1 : 0;
    if (t > 0)
      k_agg<<<512, 256, 0, stream>>>(scat, Wm, aggA, aggB);
    k_lif0fin<<<(t > 0 ? 1024 : 512), 256, 0, stream>>>(
        hmax0, S1_0, S2_0, gl[0], bl[0],
        lp[0][0], lp[0][1], lp[0][2], lp[0][3],
        stM[0], stT[0], stR[0], scat, pkb[0], init,
        aggA, aggB, gm, bm, pooled + (t > 0 ? (size_t)(t-1)*BB*512 : 0));
    for (int i = 1; i < 4; ++i) {
      int C = Cin[i], O = Oo[i];
      int twoO = 2*O, ntn = twoO/64, nConv = 32*ntn;
      const float* fin = scat + offIn[i];
      switch (Wn[i-1]) {
        case 1: k_knnconv2<1><<<512+nConv, 256, 0, stream>>>(pkb[0], idxS, S12, fin, wcat[i], AB, twoO, C, ntn); break;
        case 2: k_knnconv2<2><<<512+nConv, 256, 0, stream>>>(pkb[1], idxS, S12, fin, wcat[i], AB, twoO, C, ntn); break;
        default: k_knnconv2<4><<<512+nConv, 256, 0, stream>>>(pkb[2], idxS, S12, fin, wcat[i], AB, twoO, C, ntn); break;
      }
      k_gather<<<256, 256, 0, stream>>>(AB, O, idxS, hmaxS, S1, S2);
      k_bnlif<<<(ROWS*O)/256, 256, 0, stream>>>(
          hmaxS, oSh[i], S1, S2, gl[i], bl[i],
          lp[i][0], lp[i][1], lp[i][2], lp[i][3],
          stM[i], stT[i], stR[i], scat, offOut[i], pkb[i], init);
    }
  }
  // ---- tail: agg of t=2, finalize, output ----
  k_agg<<<512, 256, 0, stream>>>(scat, Wm, aggA, aggB);
  k_aggfin<<<512, 256, 0, stream>>>(aggA, aggB, gm, bm, pooled + (size_t)2*BB*512);
  k_final<<<4, 256, 0, stream>>>(pooled, tw, lp[4][3], (float*)d_out);
}